// Round 1
// baseline (895.417 us; speedup 1.0000x reference)
//
#include <hip/hip_runtime.h>

#define HID 50
#define IND 8
#define TLEN 512

// Fast device transcendentals: v_exp_f32 computes 2^x, v_rcp_f32 ~1ulp.
__device__ __forceinline__ float fast_sigmoid(float v) {
    float e = __builtin_amdgcn_exp2f(-1.44269504f * v);   // 2^(-x*log2e) = e^-x
    return __builtin_amdgcn_rcpf(1.0f + e);
}
__device__ __forceinline__ float fast_tanh(float v) {
    // tanh(x) = 1 - 2/(e^(2x)+1)
    float e = __builtin_amdgcn_exp2f(2.88539008f * v);    // e^(2x)
    return 1.0f - 2.0f * __builtin_amdgcn_rcpf(e + 1.0f);
}

// One wave (64 threads) per batch element. Lane i (i<50) owns hidden unit i:
// its 3 W_hh rows (r,z,n; 150 fp32) live in VGPRs for the whole sequence.
// h is broadcast between lanes via a 64-float LDS buffer, read as float4.
// Lanes 50..63 duplicate lane 49's work (clamped index) so control flow is
// wave-uniform; their h_lds slots are never read, they contribute 0 to the
// final reduction.
__global__ __launch_bounds__(64, 2) void gru_seq_kernel(
    const float* __restrict__ x,      // [B, T, 8]
    const float* __restrict__ W_ih,   // [150, 8]
    const float* __restrict__ W_hh,   // [150, 50]
    const float* __restrict__ b_ih,   // [150]
    const float* __restrict__ b_hh,   // [150]
    const float* __restrict__ W_out,  // [1, 50]
    const float* __restrict__ b_out,  // [1]
    float* __restrict__ out)          // [B] (== [B,1])
{
    const int b    = blockIdx.x;
    const int lane = threadIdx.x;
    const int i    = (lane < HID) ? lane : (HID - 1);   // clamp for uniform flow

    __shared__ __align__(16) float h_lds[64];

    // ---- Preload per-lane weights into registers (one-time) ----
    float w_r[HID], w_z[HID], w_n[HID];
#pragma unroll
    for (int j = 0; j < HID; ++j) {
        w_r[j] = W_hh[(0 * HID + i) * HID + j];
        w_z[j] = W_hh[(1 * HID + i) * HID + j];
        w_n[j] = W_hh[(2 * HID + i) * HID + j];
    }
    float wi_r[IND], wi_z[IND], wi_n[IND];
#pragma unroll
    for (int k = 0; k < IND; ++k) {
        wi_r[k] = W_ih[(0 * HID + i) * IND + k];
        wi_z[k] = W_ih[(1 * HID + i) * IND + k];
        wi_n[k] = W_ih[(2 * HID + i) * IND + k];
    }
    // r/z gates always sum gi+gh, so merge the two biases; n keeps them apart
    // because gh_n (incl. b_hh_n) is scaled by r before adding gi_n.
    const float bias_rz_r = b_ih[0 * HID + i] + b_hh[0 * HID + i];
    const float bias_rz_z = b_ih[1 * HID + i] + b_hh[1 * HID + i];
    const float bias_n_i  = b_ih[2 * HID + i];
    const float bias_n_h  = b_hh[2 * HID + i];

    float h = 0.0f;
    h_lds[lane] = 0.0f;
    __syncthreads();

    const float* xb = x + (size_t)b * TLEN * IND;

    // Software-pipeline the (wave-uniform -> scalar) x load one step ahead.
    float xv[IND];
#pragma unroll
    for (int k = 0; k < IND; ++k) xv[k] = xb[k];

    const float4* h4 = reinterpret_cast<const float4*>(h_lds);

    for (int t = 0; t < TLEN; ++t) {
        // prefetch next timestep's x (uniform address; clamped at the end)
        const int tn = (t + 1 < TLEN) ? (t + 1) : (TLEN - 1);
        float xn[IND];
#pragma unroll
        for (int k = 0; k < IND; ++k) xn[k] = xb[tn * IND + k];

        // input projection (independent of h -> covers LDS read latency)
        float gi_n = bias_n_i;
        float acc_r = bias_rz_r;
        float acc_z = bias_rz_z;
        float acc_n = bias_n_h;
#pragma unroll
        for (int k = 0; k < IND; ++k) {
            acc_r += wi_r[k] * xv[k];
            acc_z += wi_z[k] * xv[k];
            gi_n  += wi_n[k] * xv[k];
        }

        // hidden matvec: 150 FMAs fed by 12 ds_read_b128 + 1 ds_read_b64
#pragma unroll
        for (int jj = 0; jj < HID / 4; ++jj) {     // 12 float4 -> j = 0..47
            const float4 hv = h4[jj];
            const int j = jj * 4;
            acc_r += w_r[j + 0] * hv.x; acc_r += w_r[j + 1] * hv.y;
            acc_r += w_r[j + 2] * hv.z; acc_r += w_r[j + 3] * hv.w;
            acc_z += w_z[j + 0] * hv.x; acc_z += w_z[j + 1] * hv.y;
            acc_z += w_z[j + 2] * hv.z; acc_z += w_z[j + 3] * hv.w;
            acc_n += w_n[j + 0] * hv.x; acc_n += w_n[j + 1] * hv.y;
            acc_n += w_n[j + 2] * hv.z; acc_n += w_n[j + 3] * hv.w;
        }
        {
            const float h48 = h_lds[48], h49 = h_lds[49];
            acc_r += w_r[48] * h48; acc_r += w_r[49] * h49;
            acc_z += w_z[48] * h48; acc_z += w_z[49] * h49;
            acc_n += w_n[48] * h48; acc_n += w_n[49] * h49;
        }

        const float r = fast_sigmoid(acc_r);
        const float z = fast_sigmoid(acc_z);
        const float n = fast_tanh(gi_n + r * acc_n);
        h = n + z * (h - n);                 // (1-z)*n + z*h

        __syncthreads();                     // all lanes done reading old h
        h_lds[lane] = h;
        __syncthreads();                     // new h visible

#pragma unroll
        for (int k = 0; k < IND; ++k) xv[k] = xn[k];
    }

    // out[b] = sum_i h_i * W_out[i] + b_out  (wave butterfly reduction)
    float p = (lane < HID) ? h * W_out[i] : 0.0f;
#pragma unroll
    for (int m = 32; m >= 1; m >>= 1) p += __shfl_xor(p, m, 64);
    if (lane == 0) out[b] = p + b_out[0];
}

extern "C" void kernel_launch(void* const* d_in, const int* in_sizes, int n_in,
                              void* d_out, int out_size, void* d_ws, size_t ws_size,
                              hipStream_t stream) {
    const float* x     = (const float*)d_in[0];
    const float* W_ih  = (const float*)d_in[1];
    const float* W_hh  = (const float*)d_in[2];
    const float* b_ih  = (const float*)d_in[3];
    const float* b_hh  = (const float*)d_in[4];
    const float* W_out = (const float*)d_in[5];
    const float* b_out = (const float*)d_in[6];
    float* out = (float*)d_out;

    const int B = in_sizes[0] / (TLEN * IND);   // 4096
    gru_seq_kernel<<<B, 64, 0, stream>>>(x, W_ih, W_hh, b_ih, b_hh, W_out, b_out, out);
}

// Round 2
// 614.906 us; speedup vs baseline: 1.4562x; 1.4562x over previous
//
#include <hip/hip_runtime.h>

#define HID 50
#define IND 8
#define TLEN 512
#define NPAIR 25   // HID/2

typedef _Float16 h2 __attribute__((ext_vector_type(2)));

__device__ __forceinline__ float fast_sigmoid(float v) {
    float e = __builtin_amdgcn_exp2f(-1.44269504f * v);   // e^-v
    return __builtin_amdgcn_rcpf(1.0f + e);
}
__device__ __forceinline__ float fast_tanh(float v) {
    float e = __builtin_amdgcn_exp2f(2.88539008f * v);    // e^(2v)
    return 1.0f - 2.0f * __builtin_amdgcn_rcpf(e + 1.0f);
}

// One wave per batch element. Lane i owns hidden unit i; its 3 W_hh rows are
// held as PACKED fp16 pairs (75 VGPRs, not 150 fp32) so the whole working set
// fits in 128 arch VGPRs -> 4 waves/SIMD, no AGPR shuffling (round-1 killer).
// The hidden matvec uses v_dot2_f32_f16 (2 MACs/inst, fp32 accumulate).
// h state stays fp32 in lane i's register across all 512 steps; only the
// *broadcast copy* in LDS is fp16 (dot2 input), so rounding does not feed
// back into the recurrence state.
__global__ __launch_bounds__(64, 4) void gru_seq_kernel(
    const float* __restrict__ x,      // [B, T, 8]
    const float* __restrict__ W_ih,   // [150, 8]
    const float* __restrict__ W_hh,   // [150, 50]
    const float* __restrict__ b_ih,   // [150]
    const float* __restrict__ b_hh,   // [150]
    const float* __restrict__ W_out,  // [1, 50]
    const float* __restrict__ b_out,  // [1]
    float* __restrict__ out)          // [B]
{
    const int b    = blockIdx.x;
    const int lane = threadIdx.x;
    const int i    = (lane < HID) ? lane : (HID - 1);   // clamp -> uniform flow

    __shared__ __align__(16) unsigned int h_lds[32];    // 64 fp16 slots

    // ---- one-time: load + pack weights to fp16 pairs ----
    h2 w2r[NPAIR], w2z[NPAIR], w2n[NPAIR];
    {
        const float2* wr = (const float2*)(W_hh + (0 * HID + i) * HID);
        const float2* wz = (const float2*)(W_hh + (1 * HID + i) * HID);
        const float2* wn = (const float2*)(W_hh + (2 * HID + i) * HID);
#pragma unroll
        for (int j = 0; j < NPAIR; ++j) {
            float2 a = wr[j]; w2r[j] = h2{(_Float16)a.x, (_Float16)a.y};
            float2 c = wz[j]; w2z[j] = h2{(_Float16)c.x, (_Float16)c.y};
            float2 d = wn[j]; w2n[j] = h2{(_Float16)d.x, (_Float16)d.y};
        }
    }
    h2 wir[4], wiz[4], win[4];
    {
        const float2* pr = (const float2*)(W_ih + (0 * HID + i) * IND);
        const float2* pz = (const float2*)(W_ih + (1 * HID + i) * IND);
        const float2* pn = (const float2*)(W_ih + (2 * HID + i) * IND);
#pragma unroll
        for (int k = 0; k < 4; ++k) {
            float2 a = pr[k]; wir[k] = h2{(_Float16)a.x, (_Float16)a.y};
            float2 c = pz[k]; wiz[k] = h2{(_Float16)c.x, (_Float16)c.y};
            float2 d = pn[k]; win[k] = h2{(_Float16)d.x, (_Float16)d.y};
        }
    }
    const float bias_rz_r = b_ih[0 * HID + i] + b_hh[0 * HID + i];
    const float bias_rz_z = b_ih[1 * HID + i] + b_hh[1 * HID + i];
    const float bias_n_i  = b_ih[2 * HID + i];
    const float bias_n_h  = b_hh[2 * HID + i];

    float h = 0.0f;
    ((_Float16*)h_lds)[lane] = (_Float16)0.0f;
    __syncthreads();

    const float* xb = x + (size_t)b * TLEN * IND;

    // x for t=0, packed fp16
    h2 x2[4];
    {
        const float4* xr = (const float4*)xb;
        float4 a = xr[0], c = xr[1];
        x2[0] = h2{(_Float16)a.x, (_Float16)a.y};
        x2[1] = h2{(_Float16)a.z, (_Float16)a.w};
        x2[2] = h2{(_Float16)c.x, (_Float16)c.y};
        x2[3] = h2{(_Float16)c.z, (_Float16)c.w};
    }

    for (int t = 0; t < TLEN; ++t) {
        // prefetch next x (wave-uniform address; conversion deferred to loop end)
        const int tn = (t + 1 < TLEN) ? (t + 1) : (TLEN - 1);
        const float4* xr = (const float4*)(xb + tn * IND);
        const float4 xa = xr[0], xc = xr[1];

        float acc_r = bias_rz_r;
        float acc_z = bias_rz_z;
        float acc_n = bias_n_h;   // h-side of n gate (scaled by r later)
        float gi_n  = bias_n_i;   // x-side of n gate

        // input projection: 12 dot2
#pragma unroll
        for (int k = 0; k < 4; ++k) {
            acc_r = __builtin_amdgcn_fdot2(wir[k], x2[k], acc_r, false);
            acc_z = __builtin_amdgcn_fdot2(wiz[k], x2[k], acc_z, false);
            gi_n  = __builtin_amdgcn_fdot2(win[k], x2[k], gi_n,  false);
        }

        // hidden matvec: 6 uint4 LDS broadcast reads (48 halves) + 1 u32 tail,
        // each 32-bit word IS a half2 -> zero repack insts, 75 dot2 total
        const uint4* hp = (const uint4*)h_lds;
#pragma unroll
        for (int c = 0; c < 6; ++c) {
            const uint4 u = hp[c];
            const h2 ha = __builtin_bit_cast(h2, u.x);
            const h2 hb = __builtin_bit_cast(h2, u.y);
            const h2 hc = __builtin_bit_cast(h2, u.z);
            const h2 hd = __builtin_bit_cast(h2, u.w);
            acc_r = __builtin_amdgcn_fdot2(w2r[4*c+0], ha, acc_r, false);
            acc_r = __builtin_amdgcn_fdot2(w2r[4*c+1], hb, acc_r, false);
            acc_r = __builtin_amdgcn_fdot2(w2r[4*c+2], hc, acc_r, false);
            acc_r = __builtin_amdgcn_fdot2(w2r[4*c+3], hd, acc_r, false);
            acc_z = __builtin_amdgcn_fdot2(w2z[4*c+0], ha, acc_z, false);
            acc_z = __builtin_amdgcn_fdot2(w2z[4*c+1], hb, acc_z, false);
            acc_z = __builtin_amdgcn_fdot2(w2z[4*c+2], hc, acc_z, false);
            acc_z = __builtin_amdgcn_fdot2(w2z[4*c+3], hd, acc_z, false);
            acc_n = __builtin_amdgcn_fdot2(w2n[4*c+0], ha, acc_n, false);
            acc_n = __builtin_amdgcn_fdot2(w2n[4*c+1], hb, acc_n, false);
            acc_n = __builtin_amdgcn_fdot2(w2n[4*c+2], hc, acc_n, false);
            acc_n = __builtin_amdgcn_fdot2(w2n[4*c+3], hd, acc_n, false);
        }
        {
            const h2 ht = __builtin_bit_cast(h2, h_lds[24]);  // halves 48,49
            acc_r = __builtin_amdgcn_fdot2(w2r[24], ht, acc_r, false);
            acc_z = __builtin_amdgcn_fdot2(w2z[24], ht, acc_z, false);
            acc_n = __builtin_amdgcn_fdot2(w2n[24], ht, acc_n, false);
        }

        const float r = fast_sigmoid(acc_r);
        const float z = fast_sigmoid(acc_z);
        const float n = fast_tanh(gi_n + r * acc_n);
        h = n + z * (h - n);                 // fp32 state update

        __syncthreads();                     // all lanes done reading old h
        ((_Float16*)h_lds)[lane] = (_Float16)h;
        __syncthreads();                     // new h visible

        // convert prefetched x (vmem latency long hidden by now)
        x2[0] = h2{(_Float16)xa.x, (_Float16)xa.y};
        x2[1] = h2{(_Float16)xa.z, (_Float16)xa.w};
        x2[2] = h2{(_Float16)xc.x, (_Float16)xc.y};
        x2[3] = h2{(_Float16)xc.z, (_Float16)xc.w};
    }

    // out[b] = sum_i h_i * W_out[i] + b_out (fp32 butterfly reduction)
    float p = (lane < HID) ? h * W_out[i] : 0.0f;
#pragma unroll
    for (int m = 32; m >= 1; m >>= 1) p += __shfl_xor(p, m, 64);
    if (lane == 0) out[b] = p + b_out[0];
}

extern "C" void kernel_launch(void* const* d_in, const int* in_sizes, int n_in,
                              void* d_out, int out_size, void* d_ws, size_t ws_size,
                              hipStream_t stream) {
    const float* x     = (const float*)d_in[0];
    const float* W_ih  = (const float*)d_in[1];
    const float* W_hh  = (const float*)d_in[2];
    const float* b_ih  = (const float*)d_in[3];
    const float* b_hh  = (const float*)d_in[4];
    const float* W_out = (const float*)d_in[5];
    const float* b_out = (const float*)d_in[6];
    float* out = (float*)d_out;

    const int B = in_sizes[0] / (TLEN * IND);   // 4096
    gru_seq_kernel<<<B, 64, 0, stream>>>(x, W_ih, W_hh, b_ih, b_hh, W_out, b_out, out);
}

// Round 4
// 546.359 us; speedup vs baseline: 1.6389x; 1.1255x over previous
//
#include <hip/hip_runtime.h>

#define HID 50
#define IND 8
#define TLEN 512
#define NPAIR 25   // HID/2

typedef _Float16 h2 __attribute__((ext_vector_type(2)));

__device__ __forceinline__ float fast_sigmoid(float v) {
    float e = __builtin_amdgcn_exp2f(-1.44269504f * v);   // e^-v
    return __builtin_amdgcn_rcpf(1.0f + e);
}
__device__ __forceinline__ float fast_tanh(float v) {
    float e = __builtin_amdgcn_exp2f(2.88539008f * v);    // e^(2v)
    return 1.0f - 2.0f * __builtin_amdgcn_rcpf(e + 1.0f);
}

// One wave per batch element; lane i owns hidden unit i (3 W_hh rows as 75
// packed fp16-pair VGPRs, v_dot2_f32_f16 matvec, fp32 recurrence state).
//
// Round-2 lesson: true footprint ~115 regs under a 128-reg (64,4) budget made
// the allocator split 64 arch VGPR + AGPR/scratch (WRITE_SIZE 9.3MB of spill
// leak-through, 2.4x VALU inflation). Round-3/4 fix: pre-stage this block's
// whole x[b,:,:] into LDS as fp16 (8KB, one-time), so the steady loop has no
// global loads, no prefetch registers, no per-step cvt: x is ONE uniform
// broadcast ds_read_b128 per step. Steady footprint ~105 regs -> fits.
__global__ __launch_bounds__(64, 4) void gru_seq_kernel(
    const float* __restrict__ x,      // [B, T, 8]
    const float* __restrict__ W_ih,   // [150, 8]
    const float* __restrict__ W_hh,   // [150, 50]
    const float* __restrict__ b_ih,   // [150]
    const float* __restrict__ b_hh,   // [150]
    const float* __restrict__ W_out,  // [1, 50]
    const float* __restrict__ b_out,  // [1]
    float* __restrict__ out)          // [B]
{
    const int b    = blockIdx.x;
    const int lane = threadIdx.x;
    const int i    = (lane < HID) ? lane : (HID - 1);   // clamp -> uniform flow

    __shared__ __align__(16) unsigned int x_lds[TLEN * IND / 2]; // 4096 halves, 8KB
    __shared__ __align__(16) unsigned int h_lds[32];             // 64 fp16 slots

    // ---- one-time: stage x[b] to LDS as fp16 (coalesced, 16 float4/lane) ----
    {
        const float4* xg = (const float4*)(x + (size_t)b * TLEN * IND);
        uint2* xw = (uint2*)x_lds;
#pragma unroll
        for (int it = 0; it < 16; ++it) {
            const float4 v = xg[it * 64 + lane];
            const h2 p0 = h2{(_Float16)v.x, (_Float16)v.y};   // RNE cvt
            const h2 p1 = h2{(_Float16)v.z, (_Float16)v.w};
            xw[it * 64 + lane] = make_uint2(__builtin_bit_cast(unsigned int, p0),
                                            __builtin_bit_cast(unsigned int, p1));
        }
    }

    // ---- one-time: pack weights to fp16 pairs in VGPRs (RNE casts) ----
    h2 w2r[NPAIR], w2z[NPAIR], w2n[NPAIR];
    {
        const float2* wr = (const float2*)(W_hh + (0 * HID + i) * HID);
        const float2* wz = (const float2*)(W_hh + (1 * HID + i) * HID);
        const float2* wn = (const float2*)(W_hh + (2 * HID + i) * HID);
#pragma unroll
        for (int j = 0; j < NPAIR; ++j) {
            float2 a = wr[j]; w2r[j] = h2{(_Float16)a.x, (_Float16)a.y};
            float2 c = wz[j]; w2z[j] = h2{(_Float16)c.x, (_Float16)c.y};
            float2 d = wn[j]; w2n[j] = h2{(_Float16)d.x, (_Float16)d.y};
        }
    }
    h2 wir[4], wiz[4], win[4];
    {
        const float2* pr = (const float2*)(W_ih + (0 * HID + i) * IND);
        const float2* pz = (const float2*)(W_ih + (1 * HID + i) * IND);
        const float2* pn = (const float2*)(W_ih + (2 * HID + i) * IND);
#pragma unroll
        for (int k = 0; k < 4; ++k) {
            float2 a = pr[k]; wir[k] = h2{(_Float16)a.x, (_Float16)a.y};
            float2 c = pz[k]; wiz[k] = h2{(_Float16)c.x, (_Float16)c.y};
            float2 d = pn[k]; win[k] = h2{(_Float16)d.x, (_Float16)d.y};
        }
    }
    const float bias_rz_r = b_ih[0 * HID + i] + b_hh[0 * HID + i];
    const float bias_rz_z = b_ih[1 * HID + i] + b_hh[1 * HID + i];
    const float bias_n_i  = b_ih[2 * HID + i];
    const float bias_n_h  = b_hh[2 * HID + i];

    float h = 0.0f;
    ((_Float16*)h_lds)[lane] = (_Float16)0.0f;
    __syncthreads();   // x_lds + h_lds visible (single-wave WG: cheap)

    for (int t = 0; t < TLEN; ++t) {
        // x fragment: one uniform broadcast ds_read_b128 (8 halves)
        const uint4 xu = ((const uint4*)x_lds)[t];
        const h2 x0 = __builtin_bit_cast(h2, xu.x);
        const h2 x1 = __builtin_bit_cast(h2, xu.y);
        const h2 x2 = __builtin_bit_cast(h2, xu.z);
        const h2 x3 = __builtin_bit_cast(h2, xu.w);

        float acc_r = bias_rz_r;
        float acc_z = bias_rz_z;
        float acc_n = bias_n_h;   // h-side of n gate (scaled by r later)
        float gi_n  = bias_n_i;   // x-side of n gate

        // input projection: 12 dot2
        acc_r = __builtin_amdgcn_fdot2(wir[0], x0, acc_r, false);
        acc_r = __builtin_amdgcn_fdot2(wir[1], x1, acc_r, false);
        acc_r = __builtin_amdgcn_fdot2(wir[2], x2, acc_r, false);
        acc_r = __builtin_amdgcn_fdot2(wir[3], x3, acc_r, false);
        acc_z = __builtin_amdgcn_fdot2(wiz[0], x0, acc_z, false);
        acc_z = __builtin_amdgcn_fdot2(wiz[1], x1, acc_z, false);
        acc_z = __builtin_amdgcn_fdot2(wiz[2], x2, acc_z, false);
        acc_z = __builtin_amdgcn_fdot2(wiz[3], x3, acc_z, false);
        gi_n  = __builtin_amdgcn_fdot2(win[0], x0, gi_n,  false);
        gi_n  = __builtin_amdgcn_fdot2(win[1], x1, gi_n,  false);
        gi_n  = __builtin_amdgcn_fdot2(win[2], x2, gi_n,  false);
        gi_n  = __builtin_amdgcn_fdot2(win[3], x3, gi_n,  false);

        // hidden matvec: 6 uniform uint4 LDS reads + 1 u32 tail, 75 dot2
        const uint4* hp = (const uint4*)h_lds;
#pragma unroll
        for (int c = 0; c < 6; ++c) {
            const uint4 u = hp[c];
            const h2 ha = __builtin_bit_cast(h2, u.x);
            const h2 hb = __builtin_bit_cast(h2, u.y);
            const h2 hc = __builtin_bit_cast(h2, u.z);
            const h2 hd = __builtin_bit_cast(h2, u.w);
            acc_r = __builtin_amdgcn_fdot2(w2r[4*c+0], ha, acc_r, false);
            acc_r = __builtin_amdgcn_fdot2(w2r[4*c+1], hb, acc_r, false);
            acc_r = __builtin_amdgcn_fdot2(w2r[4*c+2], hc, acc_r, false);
            acc_r = __builtin_amdgcn_fdot2(w2r[4*c+3], hd, acc_r, false);
            acc_z = __builtin_amdgcn_fdot2(w2z[4*c+0], ha, acc_z, false);
            acc_z = __builtin_amdgcn_fdot2(w2z[4*c+1], hb, acc_z, false);
            acc_z = __builtin_amdgcn_fdot2(w2z[4*c+2], hc, acc_z, false);
            acc_z = __builtin_amdgcn_fdot2(w2z[4*c+3], hd, acc_z, false);
            acc_n = __builtin_amdgcn_fdot2(w2n[4*c+0], ha, acc_n, false);
            acc_n = __builtin_amdgcn_fdot2(w2n[4*c+1], hb, acc_n, false);
            acc_n = __builtin_amdgcn_fdot2(w2n[4*c+2], hc, acc_n, false);
            acc_n = __builtin_amdgcn_fdot2(w2n[4*c+3], hd, acc_n, false);
        }
        {
            const h2 ht = __builtin_bit_cast(h2, h_lds[24]);  // halves 48,49
            acc_r = __builtin_amdgcn_fdot2(w2r[24], ht, acc_r, false);
            acc_z = __builtin_amdgcn_fdot2(w2z[24], ht, acc_z, false);
            acc_n = __builtin_amdgcn_fdot2(w2n[24], ht, acc_n, false);
        }

        const float r = fast_sigmoid(acc_r);
        const float z = fast_sigmoid(acc_z);
        const float n = fast_tanh(gi_n + r * acc_n);
        h = n + z * (h - n);                 // fp32 state update

        __syncthreads();                     // single-wave WG: lowers to waitcnt
        ((_Float16*)h_lds)[lane] = (_Float16)h;   // RNE cvt
        __syncthreads();
    }

    // out[b] = sum_i h_i * W_out[i] + b_out (fp32 butterfly reduction)
    float p = (lane < HID) ? h * W_out[i] : 0.0f;
#pragma unroll
    for (int m = 32; m >= 1; m >>= 1) p += __shfl_xor(p, m, 64);
    if (lane == 0) out[b] = p + b_out[0];
}

extern "C" void kernel_launch(void* const* d_in, const int* in_sizes, int n_in,
                              void* d_out, int out_size, void* d_ws, size_t ws_size,
                              hipStream_t stream) {
    const float* x     = (const float*)d_in[0];
    const float* W_ih  = (const float*)d_in[1];
    const float* W_hh  = (const float*)d_in[2];
    const float* b_ih  = (const float*)d_in[3];
    const float* b_hh  = (const float*)d_in[4];
    const float* W_out = (const float*)d_in[5];
    const float* b_out = (const float*)d_in[6];
    float* out = (float*)d_out;

    const int B = in_sizes[0] / (TLEN * IND);   // 4096
    gru_seq_kernel<<<B, 64, 0, stream>>>(x, W_ih, W_hh, b_ih, b_hh, W_out, b_out, out);
}

// Round 5
// 365.399 us; speedup vs baseline: 2.4505x; 1.4952x over previous
//
#include <hip/hip_runtime.h>

#define HID 50
#define IND 8
#define TLEN 512
#define NB 16      // batch columns per block
#define CH 64      // x chunk length (timesteps staged in LDS)
#define GSTR 68    // G j-stride (pad 64->68: 2-way banks = free)
#define BSTR 88    // B k-stride in halves (pad 64->88: 16B-aligned rows, 2-way banks)

typedef _Float16 f16x8 __attribute__((ext_vector_type(8)));
typedef float f32x4 __attribute__((ext_vector_type(4)));

__device__ __forceinline__ float fast_sigmoid(float v) {
    float e = __builtin_amdgcn_exp2f(-1.44269504f * v);
    return __builtin_amdgcn_rcpf(1.0f + e);
}
__device__ __forceinline__ float fast_tanh(float v) {
    float e = __builtin_amdgcn_exp2f(2.88539008f * v);
    return 1.0f - 2.0f * __builtin_amdgcn_rcpf(e + 1.0f);
}

// Per timestep: G = A x B via MFMA, where
//   A [256 x 64] = rows  g*64+jh :  g=0: [W_hh_r | W_ih_r | 0]
//                                   g=1: [W_hh_z | W_ih_z | 0]
//                                   g=2: [W_hh_n |   0    | 0]
//                                   g=3: [  0    | W_ih_n | 0]   (jh>=50 rows all 0)
//   B [64 x 16]  = cols n: [h_{t-1}(50) ; x_t(8) ; 0(6)]  (fp16)
// so G0=gi_r+gh_r(+biases), G1=..z.., G2=gh_n(+b_hh_n), G3=gi_n(+b_ih_n).
// Biases enter as the MFMA C-operand. h state stays fp32 in thread registers
// (thread (j,n) persists h across steps); only matmul inputs round to fp16.
__global__ __launch_bounds__(512, 1) void gru_mfma_kernel(
    const float* __restrict__ x,      // [B, T, 8]
    const float* __restrict__ W_ih,   // [150, 8]
    const float* __restrict__ W_hh,   // [150, 50]
    const float* __restrict__ b_ih,   // [150]
    const float* __restrict__ b_hh,   // [150]
    const float* __restrict__ W_out,  // [1, 50]
    const float* __restrict__ b_out,  // [1]
    float* __restrict__ out)          // [B]
{
    const int tid  = threadIdx.x;     // 0..511, 8 waves
    const int wave = tid >> 6;
    const int lane = tid & 63;
    const int m16  = lane & 15;       // MFMA row (A) / col (B,C)
    const int quad = lane >> 4;
    const int bb   = blockIdx.x;

    __shared__ _Float16 x_lds[CH * NB * IND];   // [t&63][n][d], 16 KB
    __shared__ float    G[4 * NB * GSTR];       // [g*16+n][j(pad)], 17.4 KB
    __shared__ _Float16 B_lds[NB * BSTR];       // [n][k(pad)], 2.8 KB

    // ---- one-time: A fragments (weights) into VGPRs ----
    // Verified layouts: A[m=lane&15][k=quad*8+j]; B[k=quad*8+j][n=lane&15];
    // C/D: col=lane&15, row=quad*4+reg (m89/m118).
    const int T0 = wave * 2, T1 = wave * 2 + 1;   // this wave's M-tiles
    auto load_afrag = [&](int T, int s) -> f16x8 {
        f16x8 a;
        const int R  = T * 16 + m16;   // global M row 0..255
        const int g  = R >> 6;
        const int jh = R & 63;
#pragma unroll
        for (int j = 0; j < 8; ++j) {
            const int k = s * 32 + quad * 8 + j;
            float v = 0.f;
            if (jh < HID) {
                if (g <= 1) {
                    if (k < HID)                 v = W_hh[(g * HID + jh) * HID + k];
                    else if (k < HID + IND)      v = W_ih[(g * HID + jh) * IND + (k - HID)];
                } else if (g == 2) {
                    if (k < HID)                 v = W_hh[(2 * HID + jh) * HID + k];
                } else {
                    if (k >= HID && k < HID+IND) v = W_ih[(2 * HID + jh) * IND + (k - HID)];
                }
            }
            a[j] = (_Float16)v;
        }
        return a;
    };
    auto load_bias = [&](int T) -> f32x4 {
        f32x4 c;
#pragma unroll
        for (int r = 0; r < 4; ++r) {
            const int R  = T * 16 + quad * 4 + r;
            const int g  = R >> 6;
            const int jh = R & 63;
            float v = 0.f;
            if (jh < HID) {
                if (g == 0)      v = b_ih[jh]           + b_hh[jh];
                else if (g == 1) v = b_ih[HID + jh]     + b_hh[HID + jh];
                else if (g == 2) v = b_hh[2 * HID + jh];
                else             v = b_ih[2 * HID + jh];
            }
            c[r] = v;
        }
        return c;
    };
    const f16x8 a00 = load_afrag(T0, 0), a01 = load_afrag(T0, 1);
    const f16x8 a10 = load_afrag(T1, 0), a11 = load_afrag(T1, 1);
    const f32x4 bias0 = load_bias(T0), bias1 = load_bias(T1);

    // ---- x chunk staging: 16 KB of fp16 covering 64 timesteps ----
    auto stage_chunk = [&](int c) {
        const int n = tid >> 5;            // 0..15
        const int q = tid & 31;
        const float4* src = (const float4*)(x + ((size_t)(bb * NB + n) * TLEN + (size_t)c * CH) * IND);
#pragma unroll
        for (int r = 0; r < 4; ++r) {
            const int fidx  = q + 32 * r;  // 0..127 float4s per n-segment
            const float4 v  = src[fidx];
            const int t_rel = fidx >> 1;
            const int d     = (fidx & 1) * 4;
            _Float16* dst = &x_lds[(t_rel * NB + n) * IND + d];
            dst[0] = (_Float16)v.x; dst[1] = (_Float16)v.y;
            dst[2] = (_Float16)v.z; dst[3] = (_Float16)v.w;
        }
    };

    stage_chunk(0);
    __syncthreads();

    // ---- init B: h_{-1}=0, x_0, zero pad rows ----
    const int n0 = wave * 2;       // this thread's 2 batch columns
    const int jj = lane;           // this thread's hidden row (gate phase)
#pragma unroll
    for (int nn = 0; nn < 2; ++nn) {
        const int n = n0 + nn;
        _Float16 v = (_Float16)0.f;
        if (jj >= HID && jj < HID + IND) v = x_lds[(0 * NB + n) * IND + (jj - HID)];
        B_lds[n * BSTR + jj] = v;
    }
    float h0 = 0.f, h1 = 0.f;      // fp32 h state for (jj, n0), (jj, n0+1)

    for (int t = 0; t < TLEN; ++t) {
        __syncthreads();   // barrier A: B_lds complete, G consumed
        if ((t & (CH - 1)) == (CH - 1) && t + 1 < TLEN) stage_chunk((t + 1) >> 6);

        // B fragments: 8 consecutive k at col m16 -> one ds_read_b128 each
        const f16x8* brow = (const f16x8*)(B_lds + m16 * BSTR);
        const f16x8 bf0 = brow[quad];        // k = quad*8 .. +7
        const f16x8 bf1 = brow[4 + quad];    // k = 32 + quad*8 .. +7

        f32x4 c0 = __builtin_amdgcn_mfma_f32_16x16x32_f16(a00, bf0, bias0, 0, 0, 0);
        c0       = __builtin_amdgcn_mfma_f32_16x16x32_f16(a01, bf1, c0,    0, 0, 0);
        f32x4 c1 = __builtin_amdgcn_mfma_f32_16x16x32_f16(a10, bf0, bias1, 0, 0, 0);
        c1       = __builtin_amdgcn_mfma_f32_16x16x32_f16(a11, bf1, c1,    0, 0, 0);

        // C -> G: 4 consecutive j at fixed (g,n) -> b128
        *(f32x4*)&G[((T0 >> 2) * 16 + m16) * GSTR + (T0 & 3) * 16 + quad * 4] = c0;
        *(f32x4*)&G[((T1 >> 2) * 16 + m16) * GSTR + (T1 & 3) * 16 + quad * 4] = c1;

        __syncthreads();   // barrier B: G complete, staging complete

        // ---- gates: thread (jj, n0..n0+1) ----
        const float sr0  = G[( 0 + n0) * GSTR + jj], sr1  = G[( 0 + n0 + 1) * GSTR + jj];
        const float sz0  = G[(16 + n0) * GSTR + jj], sz1  = G[(16 + n0 + 1) * GSTR + jj];
        const float snh0 = G[(32 + n0) * GSTR + jj], snh1 = G[(32 + n0 + 1) * GSTR + jj];
        const float snx0 = G[(48 + n0) * GSTR + jj], snx1 = G[(48 + n0 + 1) * GSTR + jj];
        const float r0 = fast_sigmoid(sr0), r1 = fast_sigmoid(sr1);
        const float z0 = fast_sigmoid(sz0), z1 = fast_sigmoid(sz1);
        const float nv0 = fast_tanh(snx0 + r0 * snh0);
        const float nv1 = fast_tanh(snx1 + r1 * snh1);
        h0 = nv0 + z0 * (h0 - nv0);
        h1 = nv1 + z1 * (h1 - nv1);

        // write next-step B: h rows (fp16) and x_{t+1} rows; rows 58..63 stay 0
        if (jj < HID) {
            B_lds[ n0      * BSTR + jj] = (_Float16)h0;
            B_lds[(n0 + 1) * BSTR + jj] = (_Float16)h1;
        } else if (jj < HID + IND) {
            const int ts = (t + 1) & (CH - 1);   // t=511: dead write, in-bounds
            const int d  = jj - HID;
            B_lds[ n0      * BSTR + jj] = x_lds[(ts * NB + n0    ) * IND + d];
            B_lds[(n0 + 1) * BSTR + jj] = x_lds[(ts * NB + n0 + 1) * IND + d];
        }
    }

    // ---- head: out[b] = W_out . h_T + b_out ----
    __syncthreads();
    const float wo = (jj < HID) ? W_out[jj] : 0.f;
    G[(0 + n0    ) * GSTR + jj] = h0 * wo;
    G[(0 + n0 + 1) * GSTR + jj] = h1 * wo;
    __syncthreads();
    if (tid < NB) {
        float s = b_out[0];
        for (int j = 0; j < HID; ++j) s += G[(0 + tid) * GSTR + j];
        out[bb * NB + tid] = s;
    }
}

extern "C" void kernel_launch(void* const* d_in, const int* in_sizes, int n_in,
                              void* d_out, int out_size, void* d_ws, size_t ws_size,
                              hipStream_t stream) {
    const float* x     = (const float*)d_in[0];
    const float* W_ih  = (const float*)d_in[1];
    const float* W_hh  = (const float*)d_in[2];
    const float* b_ih  = (const float*)d_in[3];
    const float* b_hh  = (const float*)d_in[4];
    const float* W_out = (const float*)d_in[5];
    const float* b_out = (const float*)d_in[6];
    float* out = (float*)d_out;

    const int B = in_sizes[0] / (TLEN * IND);   // 4096
    gru_mfma_kernel<<<B / NB, 512, 0, stream>>>(x, W_ih, W_hh, b_ih, b_hh, W_out, b_out, out);
}

// Round 6
// 364.247 us; speedup vs baseline: 2.4583x; 1.0032x over previous
//
#include <hip/hip_runtime.h>

#define HID 50
#define IND 8
#define TLEN 512
#define NB 8          // batch columns per block (MFMA N cols 8..15 dead, stay 0)
#define CH 64         // x chunk timesteps staged in LDS
#define BSTR 88       // B row stride in halves (16B-aligned rows, benign banking)
#define NTILE 13      // ceil(4*52/16): M rows R = 4*jh + g, jh<52

typedef _Float16 f16x8 __attribute__((ext_vector_type(8)));
typedef _Float16 f16x4 __attribute__((ext_vector_type(4)));
typedef float f32x4 __attribute__((ext_vector_type(4)));

__device__ __forceinline__ float fast_sigmoid(float v) {
    float e = __builtin_amdgcn_exp2f(-1.44269504f * v);
    return __builtin_amdgcn_rcpf(1.0f + e);
}
__device__ __forceinline__ float fast_tanh(float v) {
    float e = __builtin_amdgcn_exp2f(2.88539008f * v);
    return 1.0f - 2.0f * __builtin_amdgcn_rcpf(e + 1.0f);
}

// Gate-aligned M packing: A row R = 4*jh + g (g: 0=r,1=z,2=gh_n,3=gi_n).
// For tile T, lane(quad,m16): C regs c[0..3] = the 4 gate pre-activations of
// (jh = 4T+quad, n = m16)  [C layout: col=lane&15, row=quad*4+reg].
// Gates+h update run fully in-register; h persists in fp32 regs; next-step B
// gets ONE ds_write_b16 per owned tile. No G array, no gate-read phase.
// B [64 x 16] = [h(50); x_t(8); 0(6)] fp16; biases ride in as MFMA C operand.
// Wave w owns tiles T = w + 4*tt (T<13); wave 3 also copies x rows into B.
__global__ __launch_bounds__(256, 2) void gru_mfma2(
    const float* __restrict__ x,      // [B, T, 8]
    const float* __restrict__ W_ih,   // [150, 8]
    const float* __restrict__ W_hh,   // [150, 50]
    const float* __restrict__ b_ih,   // [150]
    const float* __restrict__ b_hh,   // [150]
    const float* __restrict__ W_out,  // [1, 50]
    const float* __restrict__ b_out,  // [1]
    float* __restrict__ out)          // [B]
{
    const int tid  = threadIdx.x;     // 256 threads = 4 waves
    const int wave = tid >> 6;
    const int lane = tid & 63;
    const int m16  = lane & 15;
    const int quad = lane >> 4;
    const int bb   = blockIdx.x;

    __shared__ _Float16 x_lds[CH * NB * IND];   // [t][n][d] halves, 8 KB
    __shared__ _Float16 B_lds[16 * BSTR];       // [n][k] halves, 2.8 KB
    __shared__ float    red[NB * 56];           // head reduction scratch

    // ---- one-time: A fragments + biases into VGPRs ----
    // A layout: A[m=lane&15][k=quad*8+j]  (round-5-verified)
    auto aval = [&](int T, int k) -> float {
        const int R  = 16 * T + m16;
        const int jh = R >> 2;
        const int g  = R & 3;
        if (jh >= HID) return 0.f;
        if (g <= 1) {
            if (k < HID)            return W_hh[(g * HID + jh) * HID + k];
            if (k < HID + IND)      return W_ih[(g * HID + jh) * IND + (k - HID)];
            return 0.f;
        }
        if (g == 2) return (k < HID) ? W_hh[(2 * HID + jh) * HID + k] : 0.f;
        return (k >= HID && k < HID + IND) ? W_ih[(2 * HID + jh) * IND + (k - HID)] : 0.f;
    };

    f16x8 a0[4], a1[4];
    f32x4 bias[4];
    float h[4] = {0.f, 0.f, 0.f, 0.f};
#pragma unroll
    for (int tt = 0; tt < 4; ++tt) {
        const int T = wave + 4 * tt;
        if (T < NTILE) {
#pragma unroll
            for (int j = 0; j < 8; ++j) {
                a0[tt][j] = (_Float16)aval(T, quad * 8 + j);
                a1[tt][j] = (_Float16)aval(T, 32 + quad * 8 + j);
            }
            const int jh = 4 * T + quad;    // C-row jh for all 4 regs
#pragma unroll
            for (int r = 0; r < 4; ++r) {
                float v = 0.f;
                if (jh < HID) {
                    if (r == 0)      v = b_ih[jh] + b_hh[jh];
                    else if (r == 1) v = b_ih[HID + jh] + b_hh[HID + jh];
                    else if (r == 2) v = b_hh[2 * HID + jh];
                    else             v = b_ih[2 * HID + jh];
                }
                bias[tt][r] = v;
            }
        } else {
#pragma unroll
            for (int j = 0; j < 8; ++j) { a0[tt][j] = (_Float16)0.f; a1[tt][j] = (_Float16)0.f; }
            bias[tt] = f32x4{0.f, 0.f, 0.f, 0.f};
        }
    }

    // ---- x chunk staging: 64 timesteps -> 8 KB fp16 ----
    auto stage_chunk = [&](int c) {
        const int n = tid >> 5;        // 0..7
        const int q = tid & 31;
        const float4* src = (const float4*)(x + ((size_t)(bb * NB + n) * TLEN + (size_t)c * CH) * IND);
#pragma unroll
        for (int r = 0; r < 4; ++r) {
            const int fidx  = q + 32 * r;        // 0..127
            const float4 v  = src[fidx];
            const int t_rel = fidx >> 1;
            const int ds    = (fidx & 1) * 4;
            f16x4 pk = f16x4{(_Float16)v.x, (_Float16)v.y, (_Float16)v.z, (_Float16)v.w};
            *(f16x4*)&x_lds[t_rel * (NB * IND) + n * IND + ds] = pk;
        }
    };

    // ---- init: zero B, stage chunk 0, insert x(0) ----
    for (int idx = tid; idx < 16 * BSTR; idx += 256) B_lds[idx] = (_Float16)0.f;
    stage_chunk(0);
    __syncthreads();
    if (wave == 3 && lane < 32) {      // x rows of B for t=0
        const int n = lane >> 2, dp = (lane & 3) * 2;
        const unsigned v = *(const unsigned*)&x_lds[0 * (NB * IND) + n * IND + dp];
        *(unsigned*)&B_lds[n * BSTR + HID + dp] = v;
    }
    __syncthreads();

    for (int t = 0; t < TLEN; ++t) {
        // B(t) fragments: 2 ds_read_b128 per lane  [B layout: B[k=quad*8+j][n=m16]]
        const f16x8* brow = (const f16x8*)(B_lds + m16 * BSTR);
        const f16x8 bf0 = brow[quad];
        const f16x8 bf1 = brow[4 + quad];
        __syncthreads();               // barrier 1: all B(t) reads complete

        f32x4 c[4];
#pragma unroll
        for (int tt = 0; tt < 4; ++tt) {
            if (wave + 4 * tt < NTILE) {
                c[tt] = __builtin_amdgcn_mfma_f32_16x16x32_f16(a0[tt], bf0, bias[tt], 0, 0, 0);
                c[tt] = __builtin_amdgcn_mfma_f32_16x16x32_f16(a1[tt], bf1, c[tt],   0, 0, 0);
            }
        }

        // gates in-register; write next-step h rows of B
#pragma unroll
        for (int tt = 0; tt < 4; ++tt) {
            const int T = wave + 4 * tt;
            if (T < NTILE) {
                const int jh = 4 * T + quad;
                const float r  = fast_sigmoid(c[tt][0]);
                const float z  = fast_sigmoid(c[tt][1]);
                const float nn = fast_tanh(c[tt][3] + r * c[tt][2]);
                h[tt] = nn + z * (h[tt] - nn);
                if (m16 < NB && jh < HID)
                    B_lds[m16 * BSTR + jh] = (_Float16)h[tt];
            }
        }

        // chunk boundary: restage x (cross-wave WAR/RAW -> barriers; 8x per seq)
        if ((t & (CH - 1)) == (CH - 1) && t + 1 < TLEN) {
            __syncthreads();
            stage_chunk((t + 1) >> 6);
            __syncthreads();
        }

        // x rows of B for t+1 (wave 3; reads staged x_lds)
        if (wave == 3 && lane < 32) {
            const int t1 = (t + 1) & (CH - 1);   // t=511: dead write, in-bounds
            const int n = lane >> 2, dp = (lane & 3) * 2;
            const unsigned v = *(const unsigned*)&x_lds[t1 * (NB * IND) + n * IND + dp];
            *(unsigned*)&B_lds[n * BSTR + HID + dp] = v;
        }
        __syncthreads();               // barrier 2: B(t+1) complete
    }

    // ---- head: out[n] = sum_jh h(jh,n) * W_out[jh] + b_out ----
#pragma unroll
    for (int tt = 0; tt < 4; ++tt) {
        const int T = wave + 4 * tt;
        if (T < NTILE) {
            const int jh = 4 * T + quad;
            if (m16 < NB && jh < HID)
                red[m16 * 56 + jh] = h[tt] * W_out[jh];
        }
    }
    __syncthreads();
    if (tid < NB) {
        float s = b_out[0];
        for (int j = 0; j < HID; ++j) s += red[tid * 56 + j];
        out[bb * NB + tid] = s;
    }
}

extern "C" void kernel_launch(void* const* d_in, const int* in_sizes, int n_in,
                              void* d_out, int out_size, void* d_ws, size_t ws_size,
                              hipStream_t stream) {
    const float* x     = (const float*)d_in[0];
    const float* W_ih  = (const float*)d_in[1];
    const float* W_hh  = (const float*)d_in[2];
    const float* b_ih  = (const float*)d_in[3];
    const float* b_hh  = (const float*)d_in[4];
    const float* W_out = (const float*)d_in[5];
    const float* b_out = (const float*)d_in[6];
    float* out = (float*)d_out;

    const int B = in_sizes[0] / (TLEN * IND);   // 4096
    gru_mfma2<<<B / NB, 256, 0, stream>>>(x, W_ih, W_hh, b_ih, b_hh, W_out, b_out, out);
}